// Round 1
// baseline (254.884 us; speedup 1.0000x reference)
//
#include <hip/hip_runtime.h>
#include <stdint.h>

typedef float  f32x16 __attribute__((ext_vector_type(16)));
typedef short  s16x8  __attribute__((ext_vector_type(8)));

constexpr int D      = 64;    // feature dim (fixed by problem)
constexpr int SPLITS = 32;    // M-dimension chunks (grid.x); 32 x (N/256)=32 -> 1024 blocks = 4/CU
constexpr int TILE_M = 128;   // targets staged in LDS per tile

__device__ __forceinline__ unsigned short f2bf(float f) {
    // round-to-nearest-even fp32 -> bf16 (inputs are finite normals)
    unsigned int u = __float_as_uint(f);
    u = (u + 0x7FFFu + ((u >> 16) & 1u)) >> 16;
    return (unsigned short)u;
}

// async global->LDS DMA; LDS dest is wave-uniform base + lane*size (linear),
// swizzle is applied on the per-lane GLOBAL source address instead.
__device__ __forceinline__ void gload_lds16(const void* g, void* l) {
    __builtin_amdgcn_global_load_lds((__attribute__((address_space(1))) void*)g,
                                     (__attribute__((address_space(3))) void*)l, 16, 0, 0);
}
__device__ __forceinline__ void gload_lds4(const void* g, void* l) {
    __builtin_amdgcn_global_load_lds((__attribute__((address_space(1))) void*)g,
                                     (__attribute__((address_space(3))) void*)l, 4, 0, 0);
}

// ---- fused prep (one launch):
//  blocks [0, M/16)            : Yb = bf16(Y),      t[m]  = ||y||^2 - psi[m]
//  blocks [M/16, M/16+N/16)    : Xb = bf16(-2*X),   sqx[n] = ||x||^2
//  blocks [.., +64)            : psi partial sums -> psum_arr[64]
__global__ __launch_bounds__(256)
void prep(const float* __restrict__ X, const float* __restrict__ Y,
          const float* __restrict__ psi,
          unsigned short* __restrict__ Xb, unsigned short* __restrict__ Yb,
          float* __restrict__ t, float* __restrict__ sqx,
          float* __restrict__ psum_arr, int N, int M) {
    const int tid  = threadIdx.x;
    const int lane = tid & 63, wave = tid >> 6;
    const int r16  = lane & 15, q = lane >> 4;
    const int NYB = M >> 4, NXB = N >> 4;
    const int b = blockIdx.x;
    __shared__ float red[4];

    if (b < NYB) {
        const int row = b * 16 + wave * 4 + q;
        const float4 v = *reinterpret_cast<const float4*>(Y + (size_t)row * D + r16 * 4);
        uint2 p;
        p.x = (unsigned)f2bf(v.x) | ((unsigned)f2bf(v.y) << 16);
        p.y = (unsigned)f2bf(v.z) | ((unsigned)f2bf(v.w) << 16);
        *reinterpret_cast<uint2*>(Yb + (size_t)row * D + r16 * 4) = p;
        float s = v.x * v.x + v.y * v.y + v.z * v.z + v.w * v.w;
        #pragma unroll
        for (int off = 1; off <= 8; off <<= 1) s += __shfl_xor(s, off);
        if (r16 == 0) t[row] = s - psi[row];
    } else if (b < NYB + NXB) {
        const int row = (b - NYB) * 16 + wave * 4 + q;
        const float4 v = *reinterpret_cast<const float4*>(X + (size_t)row * D + r16 * 4);
        uint2 p;   // store -2*x in bf16: cost = (||y||^2 - psi) + <-2x, y>
        p.x = (unsigned)f2bf(-2.f * v.x) | ((unsigned)f2bf(-2.f * v.y) << 16);
        p.y = (unsigned)f2bf(-2.f * v.z) | ((unsigned)f2bf(-2.f * v.w) << 16);
        *reinterpret_cast<uint2*>(Xb + (size_t)row * D + r16 * 4) = p;
        float s = v.x * v.x + v.y * v.y + v.z * v.z + v.w * v.w;
        #pragma unroll
        for (int off = 1; off <= 8; off <<= 1) s += __shfl_xor(s, off);
        if (r16 == 0) sqx[row] = s;
    } else {
        const int g = b - NYB - NXB;            // 0..63, M == 64*512
        float s = psi[g * 512 + tid] + psi[g * 512 + 256 + tid];
        #pragma unroll
        for (int off = 1; off <= 32; off <<= 1) s += __shfl_xor(s, off);
        if (lane == 0) red[wave] = s;
        __syncthreads();
        if (tid == 0) psum_arr[g] = red[0] + red[1] + red[2] + red[3];
    }
}

// ---- main: 32x32x16 bf16 MFMA, acc initialized to t (C-operand), min epilogue.
// grid = (SPLITS, N/256); block = 256 (4 waves). Each block: 256 source rows
// (2 groups of 32 rows per wave), one M-chunk of M/SPLITS targets staged through
// double-buffered LDS via global_load_lds with source-side XOR swizzle.
__global__ __launch_bounds__(256, 4)
void sdot_main(const unsigned short* __restrict__ Xb,
               const unsigned short* __restrict__ Yb,
               const float* __restrict__ t,
               float* __restrict__ partial, int M) {
    __shared__ __align__(16) unsigned short ly[2][TILE_M * D]; // 2 x 16 KB
    __shared__ __align__(16) float lt[2][256];                 // 2 x 1 KB (128 used)

    const int tid  = threadIdx.x;
    const int wave = tid >> 6, lane = tid & 63;
    const int hi   = lane >> 5, n32 = lane & 31;
    const int chunk  = blockIdx.x;
    const int rowgrp = blockIdx.y;
    const int CH      = M / SPLITS;         // 1024
    const int m_begin = chunk * CH;
    const int NT      = CH / TILE_M;        // 8

    // A fragments: 2 row-groups x 4 K-frags; A[m=lane&31][k=(lane>>5)*8+j], k-base f*16
    s16x8 a[2][4];
    #pragma unroll
    for (int g = 0; g < 2; ++g) {
        const int srow = rowgrp * 256 + g * 128 + wave * 32 + n32;
        #pragma unroll
        for (int f = 0; f < 4; ++f)
            a[g][f] = *reinterpret_cast<const s16x8*>(Xb + (size_t)srow * D + f * 16 + hi * 8);
    }

    float rmin[2][16];
    #pragma unroll
    for (int g = 0; g < 2; ++g)
        #pragma unroll
        for (int r = 0; r < 16; ++r) rmin[g][r] = 1e30f;

    // stage one tile: 16 KB Yb (4 x 16B DMA per thread, source pre-swizzled so the
    // linear LDS image holds granule (c ^ row&7) at slot c) + 4B of t per lane.
    auto stage = [&](int buf, int mb) {
        #pragma unroll
        for (int i = 0; i < 4; ++i) {
            const int idx = i * 256 + tid;     // granule index (8 ushorts each)
            const int row = idx >> 3, c = idx & 7;
            gload_lds16(Yb + (size_t)(mb + row) * D + ((c ^ (row & 7)) << 3),
                        &ly[buf][(i * 256 + wave * 64) << 3]);
        }
        // waves 2,3 prefetch t[mb+128..255] into unused lt slots (keeps per-wave
        // vmcnt uniform); t over-read past M lands in sqx region of ws (harmless).
        gload_lds4(t + mb + wave * 64 + lane, &lt[buf][wave * 64]);
    };

    stage(0, m_begin);
    asm volatile("s_waitcnt vmcnt(0)" ::: "memory");
    __builtin_amdgcn_s_barrier();

    for (int tI = 0; tI < NT; ++tI) {
        const int buf = tI & 1;
        if (tI + 1 < NT) stage(buf ^ 1, m_begin + (tI + 1) * TILE_M);

        #pragma unroll
        for (int st = 0; st < TILE_M / 32; ++st) {
            const int trow = st * 32 + n32;    // B[n=lane&31][k=(lane>>5)*8+j]
            const int sw   = trow & 7;
            s16x8 b[4];
            #pragma unroll
            for (int f = 0; f < 4; ++f)
                b[f] = *reinterpret_cast<const s16x8*>(
                           &ly[buf][trow * D + (((2 * f + hi) ^ sw) << 3)]);
            const float tv = lt[buf][st * 32 + n32];   // ||y||^2 - psi for col n
            #pragma unroll
            for (int g = 0; g < 2; ++g) {
                f32x16 acc = {tv, tv, tv, tv, tv, tv, tv, tv,
                              tv, tv, tv, tv, tv, tv, tv, tv};
                #pragma unroll
                for (int f = 0; f < 4; ++f)
                    acc = __builtin_amdgcn_mfma_f32_32x32x16_bf16(a[g][f], b[f], acc, 0, 0, 0);
                #pragma unroll
                for (int r = 0; r < 16; ++r)
                    rmin[g][r] = fminf(rmin[g][r], acc[r]);   // acc IS the cost
            }
        }
        // 2-phase pipeline: next-tile DMA flew under the MFMAs; drain + barrier.
        asm volatile("s_waitcnt vmcnt(0)" ::: "memory");
        __builtin_amdgcn_s_barrier();
    }

    // min across target cols (lane&31) within each 32-lane half
    #pragma unroll
    for (int off = 1; off <= 16; off <<= 1)
        #pragma unroll
        for (int g = 0; g < 2; ++g)
            #pragma unroll
            for (int r = 0; r < 16; ++r)
                rmin[g][r] = fminf(rmin[g][r], __shfl_xor(rmin[g][r], off));

    if (n32 == 0) {   // lanes 0 and 32: D row = (r&3) + 8*(r>>2) + 4*hi
        #pragma unroll
        for (int g = 0; g < 2; ++g) {
            const int rowbase = rowgrp * 256 + g * 128 + wave * 32 + 4 * hi;
            #pragma unroll
            for (int r = 0; r < 16; ++r) {
                const int row = rowbase + (r & 3) + 8 * (r >> 2);
                partial[(size_t)row * SPLITS + chunk] = rmin[g][r];
            }
        }
    }
}

// ---- finalize: out[n] = ||x_n||^2 + mean(psi) + min over SPLITS partials
__global__ __launch_bounds__(256)
void finalize(const float* __restrict__ sqx, const float* __restrict__ partial,
              const float* __restrict__ psum_arr, float* __restrict__ out, int M) {
    const int lane = threadIdx.x & 63, wave = threadIdx.x >> 6;
    const int row  = blockIdx.x * 4 + wave;
    float ps = psum_arr[lane];                 // 64 partial psi sums
    #pragma unroll
    for (int off = 1; off <= 32; off <<= 1) ps += __shfl_xor(ps, off);
    float pm = (lane < SPLITS) ? partial[(size_t)row * SPLITS + lane] : 1e30f;
    #pragma unroll
    for (int off = 1; off <= 32; off <<= 1) pm = fminf(pm, __shfl_xor(pm, off));
    if (lane == 0) out[row] = sqx[row] + ps / (float)M + pm;
}

extern "C" void kernel_launch(void* const* d_in, const int* in_sizes, int n_in,
                              void* d_out, int out_size, void* d_ws, size_t ws_size,
                              hipStream_t stream) {
    const float* X   = (const float*)d_in[0];   // [N, 64]
    const float* Y   = (const float*)d_in[1];   // [M, 64]
    const float* psi = (const float*)d_in[2];   // [M]
    float* out = (float*)d_out;

    const int N = in_sizes[0] / D;   // 8192
    const int M = in_sizes[2];       // 32768

    char* ws = (char*)d_ws;
    unsigned short* Yb = (unsigned short*)ws;                  // M*64 bf16  (4 MB)
    size_t off = (size_t)M * D * sizeof(unsigned short);
    unsigned short* Xb = (unsigned short*)(ws + off);          // N*64 bf16  (1 MB)
    off += (size_t)N * D * sizeof(unsigned short);
    float* t = (float*)(ws + off);                             // M floats (128 KB)
    off += (size_t)M * sizeof(float);
    float* sqx = (float*)(ws + off);                           // N floats (32 KB; also t's over-read pad)
    off += (size_t)N * sizeof(float);
    float* partial = (float*)(ws + off);                       // N*SPLITS (1 MB)
    off += (size_t)N * SPLITS * sizeof(float);
    float* psum_arr = (float*)(ws + off);                      // 64 floats

    prep<<<(M >> 4) + (N >> 4) + 64, 256, 0, stream>>>(X, Y, psi, Xb, Yb, t, sqx, psum_arr, N, M);
    sdot_main<<<dim3(SPLITS, N / 256), 256, 0, stream>>>(Xb, Yb, t, partial, M);
    finalize<<<N / 4, 256, 0, stream>>>(sqx, partial, psum_arr, out, M);
}

// Round 2
// 97.806 us; speedup vs baseline: 2.6060x; 2.6060x over previous
//
#include <hip/hip_runtime.h>
#include <stdint.h>

typedef float  f32x4v __attribute__((ext_vector_type(4)));
typedef short  s16x8  __attribute__((ext_vector_type(8)));

constexpr int D      = 64;    // feature dim (fixed by problem)
constexpr int SPLITS = 32;    // M-dimension chunks; grid = (32, N/512) = 512 blocks
constexpr int TILE_M = 128;   // targets staged in LDS per tile
constexpr int G      = 8;     // source groups of 16 per wave -> 128 src/wave, 512/block

__device__ __forceinline__ unsigned short f2bf(float f) {
    // round-to-nearest-even fp32 -> bf16 (inputs are finite normals)
    unsigned int u = __float_as_uint(f);
    u = (u + 0x7FFFu + ((u >> 16) & 1u)) >> 16;
    return (unsigned short)u;
}

// async global->LDS DMA; LDS dest is wave-uniform base + lane*size (linear),
// swizzle applied on the per-lane GLOBAL source address instead.
__device__ __forceinline__ void gload_lds16(const void* g, void* l) {
    __builtin_amdgcn_global_load_lds((__attribute__((address_space(1))) void*)g,
                                     (__attribute__((address_space(3))) void*)l, 16, 0, 0);
}
__device__ __forceinline__ void gload_lds4(const void* g, void* l) {
    __builtin_amdgcn_global_load_lds((__attribute__((address_space(1))) void*)g,
                                     (__attribute__((address_space(3))) void*)l, 4, 0, 0);
}

// ---- fused prep (one launch):
//  blocks [0, M/16)            : Yb = bf16(Y),      t[m]  = ||y||^2 - psi[m]
//  blocks [M/16, M/16+N/16)    : Xb = bf16(-2*X),   sqx[n] = ||x||^2
//  blocks [.., +64)            : psi partial sums -> psum_arr[64]
__global__ __launch_bounds__(256)
void prep(const float* __restrict__ X, const float* __restrict__ Y,
          const float* __restrict__ psi,
          unsigned short* __restrict__ Xb, unsigned short* __restrict__ Yb,
          float* __restrict__ t, float* __restrict__ sqx,
          float* __restrict__ psum_arr, int N, int M) {
    const int tid  = threadIdx.x;
    const int lane = tid & 63, wave = tid >> 6;
    const int r16  = lane & 15, q = lane >> 4;
    const int NYB = M >> 4, NXB = N >> 4;
    const int b = blockIdx.x;
    __shared__ float red[4];

    if (b < NYB) {
        const int row = b * 16 + wave * 4 + q;
        const float4 v = *reinterpret_cast<const float4*>(Y + (size_t)row * D + r16 * 4);
        uint2 p;
        p.x = (unsigned)f2bf(v.x) | ((unsigned)f2bf(v.y) << 16);
        p.y = (unsigned)f2bf(v.z) | ((unsigned)f2bf(v.w) << 16);
        *reinterpret_cast<uint2*>(Yb + (size_t)row * D + r16 * 4) = p;
        float s = v.x * v.x + v.y * v.y + v.z * v.z + v.w * v.w;
        #pragma unroll
        for (int off = 1; off <= 8; off <<= 1) s += __shfl_xor(s, off);
        if (r16 == 0) t[row] = s - psi[row];
    } else if (b < NYB + NXB) {
        const int row = (b - NYB) * 16 + wave * 4 + q;
        const float4 v = *reinterpret_cast<const float4*>(X + (size_t)row * D + r16 * 4);
        uint2 p;   // store -2*x in bf16: cost = (||y||^2 - psi) + <-2x, y>
        p.x = (unsigned)f2bf(-2.f * v.x) | ((unsigned)f2bf(-2.f * v.y) << 16);
        p.y = (unsigned)f2bf(-2.f * v.z) | ((unsigned)f2bf(-2.f * v.w) << 16);
        *reinterpret_cast<uint2*>(Xb + (size_t)row * D + r16 * 4) = p;
        float s = v.x * v.x + v.y * v.y + v.z * v.z + v.w * v.w;
        #pragma unroll
        for (int off = 1; off <= 8; off <<= 1) s += __shfl_xor(s, off);
        if (r16 == 0) sqx[row] = s;
    } else {
        const int g = b - NYB - NXB;            // 0..63, M == 64*512
        float s = psi[g * 512 + tid] + psi[g * 512 + 256 + tid];
        #pragma unroll
        for (int off = 1; off <= 32; off <<= 1) s += __shfl_xor(s, off);
        if (lane == 0) red[wave] = s;
        __syncthreads();
        if (tid == 0) psum_arr[g] = red[0] + red[1] + red[2] + red[3];
    }
}

// ---- main: A = targets (LDS), B = sources (registers), 16x16x32 bf16 MFMA.
// C/D: col = lane&15 -> SOURCE, row = (lane>>4)*4 + r -> TARGET, so the min axis
// lives in the accumulator registers; tv = ||y||^2 - psi enters as the C-operand
// (one f32x4 ds_read, layout-exact). Per wave: G=8 source groups of 16 rows held
// as B-fragments in VGPRs; per 16-target step: 2 swizzled ds_read_b128 (A) + 1
// ds_read_b128 (tv) feed 16 MFMAs. Targets staged by global_load_lds double-buffer.
__global__ __launch_bounds__(256, 3)
void sdot_main(const unsigned short* __restrict__ Xb,
               const unsigned short* __restrict__ Yb,
               const float* __restrict__ t,
               float* __restrict__ partial, int M) {
    __shared__ __align__(16) unsigned short ly[2][TILE_M * D]; // 2 x 16 KB
    __shared__ __align__(16) float lt[2][256];                 // 2 x 1 KB (128 used)

    const int tid  = threadIdx.x;
    const int wave = tid >> 6, lane = tid & 63;
    const int quad = lane >> 4, r16 = lane & 15;
    const int chunk  = blockIdx.x;
    const int rowgrp = blockIdx.y;
    const int CH      = M / SPLITS;         // 1024
    const int m_begin = chunk * CH;
    const int NT      = CH / TILE_M;        // 8

    // B fragments: sources in regs. B[n=lane&15][k=quad*8+j], K-half h.
    s16x8 b[G][2];
    #pragma unroll
    for (int g = 0; g < G; ++g) {
        const int srow = rowgrp * (G * 64) + wave * (G * 16) + g * 16 + r16;
        #pragma unroll
        for (int h = 0; h < 2; ++h)
            b[g][h] = *reinterpret_cast<const s16x8*>(Xb + (size_t)srow * D + h * 32 + quad * 8);
    }

    float rmin[G];
    #pragma unroll
    for (int g = 0; g < G; ++g) rmin[g] = 1e30f;

    // stage one tile: 16 KB Yb (4 x 16B DMA/thread; source pre-swizzled so linear
    // LDS slot c holds logical granule c^(row&7)) + t values into lt.
    auto stage = [&](int buf, int mb) {
        #pragma unroll
        for (int i = 0; i < 4; ++i) {
            const int idx = i * 256 + tid;     // granule index (8 ushorts each)
            const int row = idx >> 3, c = idx & 7;
            gload_lds16(Yb + (size_t)(mb + row) * D + ((c ^ (row & 7)) << 3),
                        &ly[buf][(i * 256 + wave * 64) << 3]);
        }
        // waves 2,3 land in lt[128..255] (t over-read past M hits sqx region: harmless)
        gload_lds4(t + mb + wave * 64 + lane, &lt[buf][wave * 64]);
    };

    stage(0, m_begin);
    asm volatile("s_waitcnt vmcnt(0)" ::: "memory");
    __builtin_amdgcn_s_barrier();

    for (int tI = 0; tI < NT; ++tI) {
        const int buf = tI & 1;
        if (tI + 1 < NT) stage(buf ^ 1, m_begin + (tI + 1) * TILE_M);

        #pragma unroll
        for (int st = 0; st < TILE_M / 16; ++st) {
            const int trow = st * 16 + r16;    // A[m=lane&15][k=quad*8+j]
            const int sw   = trow & 7;
            const s16x8 a0 = *reinterpret_cast<const s16x8*>(
                                 &ly[buf][trow * D + ((quad ^ sw) << 3)]);
            const s16x8 a1 = *reinterpret_cast<const s16x8*>(
                                 &ly[buf][trow * D + (((quad + 4) ^ sw) << 3)]);
            // tv for this lane's 4 accumulator rows: m = st*16 + (lane>>4)*4 + r
            const f32x4v tv4 = *reinterpret_cast<const f32x4v*>(
                                   &lt[buf][st * 16 + quad * 4]);
            #pragma unroll
            for (int g = 0; g < G; ++g) {
                f32x4v acc = __builtin_amdgcn_mfma_f32_16x16x32_bf16(a0, b[g][0], tv4, 0, 0, 0);
                acc        = __builtin_amdgcn_mfma_f32_16x16x32_bf16(a1, b[g][1], acc, 0, 0, 0);
                // acc[r] IS cost(target row r, source col); min over rows in-register
                rmin[g] = fminf(fminf(fminf(acc[0], acc[1]), acc[2]),
                                fminf(acc[3], rmin[g]));
            }
        }
        // 2-phase pipeline: next-tile DMA flew under the MFMAs; drain + barrier.
        asm volatile("s_waitcnt vmcnt(0)" ::: "memory");
        __builtin_amdgcn_s_barrier();
    }

    // min across the 4 row-block lane groups (lanes l, l^16, l^32, l^48 share col)
    #pragma unroll
    for (int off = 16; off <= 32; off <<= 1)
        #pragma unroll
        for (int g = 0; g < G; ++g)
            rmin[g] = fminf(rmin[g], __shfl_xor(rmin[g], off));

    if (quad == 0) {   // lanes 0..15: col n = r16
        #pragma unroll
        for (int g = 0; g < G; ++g) {
            const int row = rowgrp * (G * 64) + wave * (G * 16) + g * 16 + r16;
            partial[(size_t)row * SPLITS + chunk] = rmin[g];
        }
    }
}

// ---- finalize: out[n] = ||x_n||^2 + mean(psi) + min over SPLITS partials
__global__ __launch_bounds__(256)
void finalize(const float* __restrict__ sqx, const float* __restrict__ partial,
              const float* __restrict__ psum_arr, float* __restrict__ out, int M) {
    const int lane = threadIdx.x & 63, wave = threadIdx.x >> 6;
    const int row  = blockIdx.x * 4 + wave;
    float ps = psum_arr[lane];                 // 64 partial psi sums
    #pragma unroll
    for (int off = 1; off <= 32; off <<= 1) ps += __shfl_xor(ps, off);
    float pm = (lane < SPLITS) ? partial[(size_t)row * SPLITS + lane] : 1e30f;
    #pragma unroll
    for (int off = 1; off <= 32; off <<= 1) pm = fminf(pm, __shfl_xor(pm, off));
    if (lane == 0) out[row] = sqx[row] + ps / (float)M + pm;
}

extern "C" void kernel_launch(void* const* d_in, const int* in_sizes, int n_in,
                              void* d_out, int out_size, void* d_ws, size_t ws_size,
                              hipStream_t stream) {
    const float* X   = (const float*)d_in[0];   // [N, 64]
    const float* Y   = (const float*)d_in[1];   // [M, 64]
    const float* psi = (const float*)d_in[2];   // [M]
    float* out = (float*)d_out;

    const int N = in_sizes[0] / D;   // 8192
    const int M = in_sizes[2];       // 32768

    char* ws = (char*)d_ws;
    unsigned short* Yb = (unsigned short*)ws;                  // M*64 bf16  (4 MB)
    size_t off = (size_t)M * D * sizeof(unsigned short);
    unsigned short* Xb = (unsigned short*)(ws + off);          // N*64 bf16  (1 MB)
    off += (size_t)N * D * sizeof(unsigned short);
    float* t = (float*)(ws + off);                             // M floats (128 KB)
    off += (size_t)M * sizeof(float);
    float* sqx = (float*)(ws + off);                           // N floats (32 KB; also t's over-read pad)
    off += (size_t)N * sizeof(float);
    float* partial = (float*)(ws + off);                       // N*SPLITS (1 MB)
    off += (size_t)N * SPLITS * sizeof(float);
    float* psum_arr = (float*)(ws + off);                      // 64 floats

    prep<<<(M >> 4) + (N >> 4) + 64, 256, 0, stream>>>(X, Y, psi, Xb, Yb, t, sqx, psum_arr, N, M);
    sdot_main<<<dim3(SPLITS, N / 512), 256, 0, stream>>>(Xb, Yb, t, partial, M);
    finalize<<<N / 4, 256, 0, stream>>>(sqx, partial, psum_arr, out, M);
}